// Round 2
// baseline (903.370 us; speedup 1.0000x reference)
//
#include <hip/hip_runtime.h>

typedef unsigned short u16;
typedef unsigned int   u32;

#define EPS 1e-5f

// ---- converted-weights layout inside wbuf (float offsets) ----
constexpr int OFF_W1 = 0;              // 256*64
constexpr int OFF_B1 = 16384;          // 64
constexpr int OFF_G1 = 16448;          // 64
constexpr int OFF_BE1 = 16512;         // 64
constexpr int OFF_W2 = 16576;          // 64*64
constexpr int OFF_B2 = 20672;          // 64
constexpr int OFF_REL = 20736;         // 7*64
constexpr int OFF_WM1 = 21184;         // 193*64
constexpr int OFF_BM1 = 33536;         // 64
constexpr int OFF_WM2 = 33600;         // 64*64
constexpr int OFF_BM2 = 37696;         // 64
constexpr int OFF_GN = 37760;          // 64
constexpr int OFF_BN = 37824;          // 64
constexpr int OFF_WG1 = 37888;         // 128*64
constexpr int OFF_BG1 = 46080;         // 64
constexpr int OFF_WG2 = 46144;         // 64*64
constexpr int OFF_BG2 = 50240;         // 64
constexpr int WTOT = 50304;

__device__ __forceinline__ float bf2f(u32 u) { return __uint_as_float(u << 16); }
__device__ __forceinline__ u16 f2bf(float f) {
  u32 b = __float_as_uint(f);
  return (u16)((b + 0x7fffu + ((b >> 16) & 1u)) >> 16);  // RNE
}
// monotone float->u32 key for atomicMax (finite floats only; all keys > 0)
__device__ __forceinline__ u32 fkey(float f) {
  u32 b = __float_as_uint(f);
  return (b & 0x80000000u) ? ~b : (b | 0x80000000u);
}

// ---- dtype probe: are inputs float32 (1) or bf16 (0)? ----
// fp32 typed_edges: column 0 (src) is exactly integral for every edge.
// bf16 data misread as fp32 has random fractional bits -> fails w.h.p.
__launch_bounds__(64)
__global__ void k_detect(const void* te, int* flag) {
  const float* tf = (const float*)te;
  int i = threadIdx.x;
  float v = tf[4 * i];             // 64 samples, 1 KB span (safe in either dtype)
  bool ok = (v >= 0.f) && (v < 16777216.f) && (v == floorf(v));
  unsigned long long m = __ballot(ok);
  if (i == 0) *flag = (m == ~0ull) ? 1 : 0;
}

struct PrepArgs { const void* p[17]; };

// ---- normalize all weights/biases to fp32 in wbuf (handles both dtypes) ----
__launch_bounds__(256)
__global__ void k_prep(PrepArgs a, float* __restrict__ wbuf, const int* __restrict__ flag) {
  constexpr int sz[17]  = {16384,64,64,64,4096,64,448,12352,64,4096,64,64,64,8192,64,4096,64};
  constexpr int off[17] = {OFF_W1,OFF_B1,OFF_G1,OFF_BE1,OFF_W2,OFF_B2,OFF_REL,OFF_WM1,
                           OFF_BM1,OFF_WM2,OFF_BM2,OFF_GN,OFF_BN,OFF_WG1,OFF_BG1,OFF_WG2,OFF_BG2};
  int f32 = *flag;
  int tid = blockIdx.x * blockDim.x + threadIdx.x;
  int nth = gridDim.x * blockDim.x;
  #pragma unroll
  for (int i = 0; i < 17; i++) {
    float* d = wbuf + off[i];
    if (f32) {
      const float* s = (const float*)a.p[i];
      for (int k = tid; k < sz[i]; k += nth) d[k] = s[k];
    } else {
      const u16* s = (const u16*)a.p[i];
      for (int k = tid; k < sz[i]; k += nth) d[k] = bf2f(s[k]);
    }
  }
}

// ---- stage A: h = relu(relu(LN(X@W1+b1,g1,be1)) @ W2 + b2), lane-per-node ----
__launch_bounds__(256)
__global__ void k_h(const void* __restrict__ X, const float* __restrict__ wb,
                    float* __restrict__ h, int N, const int* __restrict__ flag) {
  int n = blockIdx.x * 256 + threadIdx.x;
  if (n >= N) return;
  int f32 = *flag;
  const float* W1 = wb + OFF_W1;
  const float* b1 = wb + OFF_B1;
  const float* g1 = wb + OFF_G1;
  const float* be1 = wb + OFF_BE1;
  const float* W2 = wb + OFF_W2;
  const float* b2 = wb + OFF_B2;

  float acc[64];
  #pragma unroll
  for (int j = 0; j < 64; j++) acc[j] = b1[j];

  #pragma unroll 1
  for (int kc = 0; kc < 32; kc++) {
    float xv[8];
    if (f32) {
      const float* xr = (const float*)X + (size_t)n * 256 + kc * 8;
      float4 u0 = *(const float4*)xr;
      float4 u1 = *(const float4*)(xr + 4);
      xv[0] = u0.x; xv[1] = u0.y; xv[2] = u0.z; xv[3] = u0.w;
      xv[4] = u1.x; xv[5] = u1.y; xv[6] = u1.z; xv[7] = u1.w;
    } else {
      const u16* xr = (const u16*)X + (size_t)n * 256 + kc * 8;
      uint4 u = *(const uint4*)xr;
      xv[0] = bf2f(u.x & 0xffffu); xv[1] = bf2f(u.x >> 16);
      xv[2] = bf2f(u.y & 0xffffu); xv[3] = bf2f(u.y >> 16);
      xv[4] = bf2f(u.z & 0xffffu); xv[5] = bf2f(u.z >> 16);
      xv[6] = bf2f(u.w & 0xffffu); xv[7] = bf2f(u.w >> 16);
    }
    #pragma unroll
    for (int m = 0; m < 8; m++) {
      const float* wr = W1 + (kc * 8 + m) * 64;
      #pragma unroll
      for (int j = 0; j < 64; j++) acc[j] = fmaf(xv[m], wr[j], acc[j]);
    }
  }

  float mu = 0.f;
  #pragma unroll
  for (int j = 0; j < 64; j++) mu += acc[j];
  mu *= (1.f / 64.f);
  float var = 0.f;
  #pragma unroll
  for (int j = 0; j < 64; j++) { float d = acc[j] - mu; var += d * d; }
  var *= (1.f / 64.f);
  float rs = rsqrtf(var + EPS);

  float h1[64];
  #pragma unroll
  for (int j = 0; j < 64; j++)
    h1[j] = fmaxf(fmaf((acc[j] - mu) * rs, g1[j], be1[j]), 0.f);

  float a2[64];
  #pragma unroll
  for (int j = 0; j < 64; j++) a2[j] = b2[j];
  #pragma unroll
  for (int k = 0; k < 64; k++) {
    const float* wr = W2 + k * 64;
    float tv = h1[k];
    #pragma unroll
    for (int j = 0; j < 64; j++) a2[j] = fmaf(tv, wr[j], a2[j]);
  }

  float* hr = h + (size_t)n * 64;
  #pragma unroll
  for (int jc = 0; jc < 16; jc++) {
    float4 v = make_float4(fmaxf(a2[jc * 4 + 0], 0.f), fmaxf(a2[jc * 4 + 1], 0.f),
                           fmaxf(a2[jc * 4 + 2], 0.f), fmaxf(a2[jc * 4 + 3], 0.f));
    *(float4*)(hr + jc * 4) = v;
  }
}

// ---- stage B+C: per-edge message MLP + atomic segment-sum, lane-per-edge ----
__launch_bounds__(256)
__global__ void k_edge(const void* __restrict__ te, const float* __restrict__ h,
                       const float* __restrict__ wb, float* __restrict__ agg,
                       int Ecnt, int N, const int* __restrict__ flag) {
  __shared__ float lmsg[4][64 * 17];
  __shared__ int ldst[4][64];
  int tid = threadIdx.x;
  int wave = tid >> 6, lane = tid & 63;
  int e = blockIdx.x * 256 + tid;
  int ec = (e < Ecnt) ? e : 0;
  int f32 = *flag;

  int src, dst, rel; float w;
  if (f32) {
    const float* tf = (const float*)te + (size_t)ec * 4;
    float4 v = *(const float4*)tf;
    src = (int)v.x; dst = (int)v.y; rel = (int)v.z; w = v.w;
  } else {
    const u16* tu = (const u16*)te + (size_t)ec * 4;
    uint2 tr = *(const uint2*)tu;
    src = (int)bf2f(tr.x & 0xffffu); dst = (int)bf2f(tr.x >> 16);
    rel = (int)bf2f(tr.y & 0xffffu); w = bf2f(tr.y >> 16);
  }
  // clamp: no OOB regardless of dtype interpretation
  src = min(max(src, 0), N - 1);
  dst = min(max(dst, 0), N - 1);
  rel = min(max(rel, 0), 6);
  ldst[wave][lane] = dst;

  const float* Wm1 = wb + OFF_WM1;
  const float* bm1 = wb + OFF_BM1;
  const float* Wm2 = wb + OFF_WM2;
  const float* bm2 = wb + OFF_BM2;

  float acc[64];
  #pragma unroll
  for (int j = 0; j < 64; j++) acc[j] = bm1[j];

  const float* hs = h + (size_t)src * 64;
  const float* hd = h + (size_t)dst * 64;
  const float* rr = wb + OFF_REL + rel * 64;

  #pragma unroll 1
  for (int kc = 0; kc < 16; kc++) {
    float4 a = *(const float4*)(hs + kc * 4);
    float4 b = *(const float4*)(hd + kc * 4);
    float4 c = *(const float4*)(rr + kc * 4);
    float av[4] = {a.x, a.y, a.z, a.w};
    float bv[4] = {b.x, b.y, b.z, b.w};
    float cv[4] = {c.x, c.y, c.z, c.w};
    #pragma unroll
    for (int m = 0; m < 4; m++) {
      int k = kc * 4 + m;
      const float* w0 = Wm1 + k * 64;
      const float* w1 = Wm1 + (64 + k) * 64;
      const float* w2 = Wm1 + (128 + k) * 64;
      #pragma unroll
      for (int j = 0; j < 64; j++) {
        acc[j] = fmaf(av[m], w0[j], acc[j]);
        acc[j] = fmaf(bv[m], w1[j], acc[j]);
        acc[j] = fmaf(cv[m], w2[j], acc[j]);
      }
    }
  }
  {
    const float* w3 = Wm1 + 192 * 64;
    #pragma unroll
    for (int j = 0; j < 64; j++) acc[j] = fmaf(w, w3[j], acc[j]);
  }
  #pragma unroll
  for (int j = 0; j < 64; j++) acc[j] = fmaxf(acc[j], 0.f);  // t = relu(.)

  int ebase = blockIdx.x * 256 + wave * 64;
  #pragma unroll
  for (int jc = 0; jc < 4; jc++) {
    float a2[16];
    #pragma unroll
    for (int jj = 0; jj < 16; jj++) a2[jj] = bm2[jc * 16 + jj];
    #pragma unroll
    for (int k = 0; k < 64; k++) {
      const float* wr = Wm2 + k * 64 + jc * 16;
      float tv = acc[k];
      #pragma unroll
      for (int jj = 0; jj < 16; jj++) a2[jj] = fmaf(tv, wr[jj], a2[jj]);
    }
    // wave-local transpose through LDS -> row-coalesced atomics
    #pragma unroll
    for (int jj = 0; jj < 16; jj++) lmsg[wave][lane * 17 + jj] = a2[jj];
    __builtin_amdgcn_wave_barrier();
    #pragma unroll
    for (int g4 = 0; g4 < 16; g4++) {
      int esub = g4 * 4 + (lane >> 4);
      int jj2 = lane & 15;
      if (ebase + esub < Ecnt) {
        int de = ldst[wave][esub];
        atomicAdd(agg + (size_t)de * 64 + jc * 16 + jj2, lmsg[wave][esub * 17 + jj2]);
      }
    }
    __builtin_amdgcn_wave_barrier();
  }
}

// ---- stage D1: nodes = LN(h+agg,gn,bn); accumulate global mean-sum and max ----
__launch_bounds__(256)
__global__ void k_nodes(const float* __restrict__ h, const float* __restrict__ agg,
                        const float* __restrict__ wb, float* __restrict__ gsum,
                        u32* __restrict__ gmax, int N) {
  int lane = threadIdx.x & 63, wave = threadIdx.x >> 6;
  int wid = blockIdx.x * 4 + wave;
  int nw = gridDim.x * 4;
  float gn = wb[OFF_GN + lane], bn = wb[OFF_BN + lane];
  float sj = 0.f, mj = -3.0e38f;
  for (int n = wid; n < N; n += nw) {
    float v = h[(size_t)n * 64 + lane] + agg[(size_t)n * 64 + lane];
    float s = v;
    #pragma unroll
    for (int m = 32; m >= 1; m >>= 1) s += __shfl_xor(s, m, 64);
    float mu = s * (1.f / 64.f);
    float d = v - mu;
    float q = d * d;
    #pragma unroll
    for (int m = 32; m >= 1; m >>= 1) q += __shfl_xor(q, m, 64);
    float rs = rsqrtf(q * (1.f / 64.f) + EPS);
    float val = fmaf(d * rs, gn, bn);
    sj += val;
    mj = fmaxf(mj, val);
  }
  __shared__ float bs[256], bm[256];
  bs[threadIdx.x] = sj;
  bm[threadIdx.x] = mj;
  __syncthreads();
  if (threadIdx.x < 64) {
    int t = threadIdx.x;
    float ts = bs[t] + bs[64 + t] + bs[128 + t] + bs[192 + t];
    float tm = fmaxf(fmaxf(bm[t], bm[64 + t]), fmaxf(bm[128 + t], bm[192 + t]));
    atomicAdd(gsum + t, ts);
    atomicMax(gmax + t, fkey(tm));
  }
}

// ---- stage D2: g=[mean,max]; out = relu(g@Wg1+bg1)@Wg2+bg2 ----
__launch_bounds__(128)
__global__ void k_final(const float* __restrict__ wb, const float* __restrict__ gsum,
                        const u32* __restrict__ gmax, void* __restrict__ out, int N,
                        const int* __restrict__ flag) {
  __shared__ float g[128];
  __shared__ float y1[64];
  int t = threadIdx.x;
  if (t < 64) {
    g[t] = gsum[t] / (float)N;
  } else {
    u32 k = gmax[t - 64];
    u32 b = (k & 0x80000000u) ? (k & 0x7fffffffu) : ~k;
    g[t] = __uint_as_float(b);
  }
  __syncthreads();
  if (t < 64) {
    float a = wb[OFF_BG1 + t];
    for (int i = 0; i < 128; i++) a = fmaf(g[i], wb[OFF_WG1 + i * 64 + t], a);
    y1[t] = fmaxf(a, 0.f);
  }
  __syncthreads();
  if (t < 64) {
    float a = wb[OFF_BG2 + t];
    for (int k = 0; k < 64; k++) a = fmaf(y1[k], wb[OFF_WG2 + k * 64 + t], a);
    if (*flag) ((float*)out)[t] = a;
    else       ((u16*)out)[t] = f2bf(a);
  }
}

extern "C" void kernel_launch(void* const* d_in, const int* in_sizes, int n_in,
                              void* d_out, int out_size, void* d_ws, size_t ws_size,
                              hipStream_t stream) {
  const int N = in_sizes[0] / 256;
  const int E = in_sizes[1] / 4;

  float* ws = (float*)d_ws;
  float* h = ws;                               // N*64 f32
  float* agg = ws + (size_t)N * 64;            // N*64 f32
  float* gsum = agg + (size_t)N * 64;          // 64 f32
  u32* gmax = (u32*)(gsum + 64);               // 64 u32
  int* flag = (int*)(gsum + 128);              // 1 int (outside memset range)
  float* wbuf = gsum + 192;                    // WTOT f32, 16B-aligned

  PrepArgs pa;
  for (int i = 0; i < 17; i++) pa.p[i] = d_in[2 + i];

  hipLaunchKernelGGL(k_detect, dim3(1), dim3(64), 0, stream, d_in[1], flag);
  hipLaunchKernelGGL(k_prep, dim3(16), dim3(256), 0, stream, pa, wbuf, flag);
  hipMemsetAsync(agg, 0, ((size_t)N * 64 + 128) * sizeof(float), stream);
  hipLaunchKernelGGL(k_h, dim3((N + 255) / 256), dim3(256), 0, stream,
                     d_in[0], wbuf, h, N, flag);
  hipLaunchKernelGGL(k_edge, dim3((E + 255) / 256), dim3(256), 0, stream,
                     d_in[1], h, wbuf, agg, E, N, flag);
  hipLaunchKernelGGL(k_nodes, dim3(2048), dim3(256), 0, stream, h, agg, wbuf, gsum, gmax, N);
  hipLaunchKernelGGL(k_final, dim3(1), dim3(128), 0, stream, wbuf, gsum, gmax, d_out, N, flag);
}

// Round 3
// 442.566 us; speedup vs baseline: 2.0412x; 2.0412x over previous
//
#include <hip/hip_runtime.h>

typedef unsigned short u16;
typedef unsigned int   u32;
typedef __attribute__((ext_vector_type(8))) short bf16x8;   // 8 bf16 (4 VGPRs)
typedef __attribute__((ext_vector_type(4))) float f32x4;    // mfma acc

#define EPS 1e-5f
#define MFMA(a,b,c) __builtin_amdgcn_mfma_f32_16x16x32_bf16(a,b,c,0,0,0)

// ---- wbuf (fp32) element offsets ----
constexpr int OB_b1=0, OB_g1=64, OB_be1=128, OB_b2=192, OB_bm1=256, OB_w192=320,
              OB_bm2=384, OB_gn=448, OB_bn=512, OB_bg1=576, OB_bg2=640,
              OB_Wg1=704, OB_Wg2=8896, WB_TOT=12992;
// ---- frag buffer (u16/bf16) element offsets ----
// B-frag order: frag f=(ks*4+nt), element ((f*64)+lane)*8+j = W[ks*32+(lane>>4)*8+j][nt*16+(lane&15)]
constexpr int FR_Wm1=0;          // 24 frags (K=192) = 12288
constexpr int FR_Wm2=12288;      // 8 frags  (K=64)  = 4096
constexpr int FR_rel=16384;      // 7 rows x 80 (pad) = 560, alloc 576
constexpr int FR_W1 =16960;      // 32 frags (K=256) = 16384
constexpr int FR_W2 =33344;      // 8 frags  (K=64)  = 4096
constexpr int FR_TOT=37440;

__device__ __forceinline__ float bf2f(u32 u) { return __uint_as_float(u << 16); }
__device__ __forceinline__ u16 f2bf(float f) {
  u32 b = __float_as_uint(f);
  return (u16)((b + 0x7fffu + ((b >> 16) & 1u)) >> 16);  // RNE
}
__device__ __forceinline__ u32 fkey(float f) {  // monotone float->u32 (finite)
  u32 b = __float_as_uint(f);
  return (b & 0x80000000u) ? ~b : (b | 0x80000000u);
}

// ---- prep: fp32 misc into wbuf; swizzle weights into bf16 B-frag layout ----
__launch_bounds__(256)
__global__ void k_prep(const float* __restrict__ W1, const float* __restrict__ b1,
                       const float* __restrict__ g1, const float* __restrict__ be1,
                       const float* __restrict__ W2, const float* __restrict__ b2,
                       const float* __restrict__ rel_emb,
                       const float* __restrict__ Wm1, const float* __restrict__ bm1,
                       const float* __restrict__ Wm2, const float* __restrict__ bm2,
                       const float* __restrict__ gn, const float* __restrict__ bn,
                       const float* __restrict__ Wg1, const float* __restrict__ bg1,
                       const float* __restrict__ Wg2, const float* __restrict__ bg2,
                       float* __restrict__ wbuf, u16* __restrict__ frags) {
  int tid = blockIdx.x * 256 + threadIdx.x;
  int nth = gridDim.x * 256;
  for (int i = tid; i < 64; i += nth) {
    wbuf[OB_b1 + i] = b1[i];   wbuf[OB_g1 + i] = g1[i];
    wbuf[OB_be1 + i] = be1[i]; wbuf[OB_b2 + i] = b2[i];
    wbuf[OB_bm1 + i] = bm1[i]; wbuf[OB_w192 + i] = Wm1[192 * 64 + i];
    wbuf[OB_bm2 + i] = bm2[i]; wbuf[OB_gn + i] = gn[i];
    wbuf[OB_bn + i] = bn[i];   wbuf[OB_bg1 + i] = bg1[i];
    wbuf[OB_bg2 + i] = bg2[i];
  }
  for (int i = tid; i < 8192; i += nth) wbuf[OB_Wg1 + i] = Wg1[i];
  for (int i = tid; i < 4096; i += nth) wbuf[OB_Wg2 + i] = Wg2[i];
  // swizzles: idx -> f=idx>>9, L=(idx>>3)&63, j=idx&7
  for (int idx = tid; idx < 16384; idx += nth) {
    int f = idx >> 9, L = (idx >> 3) & 63, j = idx & 7;
    int k = (f >> 2) * 32 + ((L >> 4) << 3) + j, n = ((f & 3) << 4) + (L & 15);
    frags[FR_W1 + idx] = f2bf(W1[k * 64 + n]);
  }
  for (int idx = tid; idx < 4096; idx += nth) {
    int f = idx >> 9, L = (idx >> 3) & 63, j = idx & 7;
    int k = (f >> 2) * 32 + ((L >> 4) << 3) + j, n = ((f & 3) << 4) + (L & 15);
    frags[FR_W2 + idx] = f2bf(W2[k * 64 + n]);
  }
  for (int idx = tid; idx < 12288; idx += nth) {
    int f = idx >> 9, L = (idx >> 3) & 63, j = idx & 7;
    int k = (f >> 2) * 32 + ((L >> 4) << 3) + j, n = ((f & 3) << 4) + (L & 15);
    frags[FR_Wm1 + idx] = f2bf(Wm1[k * 64 + n]);
  }
  for (int idx = tid; idx < 4096; idx += nth) {
    int f = idx >> 9, L = (idx >> 3) & 63, j = idx & 7;
    int k = (f >> 2) * 32 + ((L >> 4) << 3) + j, n = ((f & 3) << 4) + (L & 15);
    frags[FR_Wm2 + idx] = f2bf(Wm2[k * 64 + n]);
  }
  for (int idx = tid; idx < 576; idx += nth) {
    int r = idx / 80, c = idx % 80;
    frags[FR_rel + idx] = (r < 7 && c < 64) ? f2bf(rel_emb[r * 64 + c]) : (u16)0;
  }
}

// ---- stage A (MFMA): h = relu(relu(LN(X@W1+b1)) @ W2 + b2) -> bf16 ----
__launch_bounds__(256, 3)
__global__ void k_h(const float* __restrict__ X, const float* __restrict__ wbuf,
                    const u16* __restrict__ frags, u16* __restrict__ hb, int N) {
  __shared__ __align__(16) u16 sW1[32 * 512];
  __shared__ __align__(16) u16 sW2[8 * 512];
  __shared__ __align__(16) u16 st[4][16 * 72];

  // preload W1/W2 frags (20480 el = 2560 uint4)
  {
    const uint4* srcp = (const uint4*)(frags + FR_W1);
    uint4* d1 = (uint4*)sW1;  // sW1 (2048 uint4) then sW2 (512 uint4) contiguous? not guaranteed; split
    for (int i = threadIdx.x; i < 2048; i += 256) d1[i] = srcp[i];
    const uint4* srcp2 = (const uint4*)(frags + FR_W2);
    uint4* d2 = (uint4*)sW2;
    for (int i = threadIdx.x; i < 512; i += 256) d2[i] = srcp2[i];
  }
  __syncthreads();

  int lane = threadIdx.x & 63, wave = threadIdx.x >> 6;
  int m = lane & 15, quad = lane >> 4, koff = quad * 8, col0 = m;

  float b1v[4], g1v[4], be1v[4], b2v[4];
  #pragma unroll
  for (int nt = 0; nt < 4; nt++) {
    int c = nt * 16 + col0;
    b1v[nt] = wbuf[OB_b1 + c]; g1v[nt] = wbuf[OB_g1 + c];
    be1v[nt] = wbuf[OB_be1 + c]; b2v[nt] = wbuf[OB_b2 + c];
  }

  int ntiles = (N + 15) / 16;
  int wid = blockIdx.x * 4 + wave, nw = gridDim.x * 4;
  for (int tile = wid; tile < ntiles; tile += nw) {
    int n0 = tile * 16;
    int nm = min(n0 + m, N - 1);
    const float* xr = X + (size_t)nm * 256 + koff;

    f32x4 acc[4] = {};
    #pragma unroll 1
    for (int ks = 0; ks < 8; ks++) {
      float4 u0 = *(const float4*)(xr + ks * 32);
      float4 u1 = *(const float4*)(xr + ks * 32 + 4);
      bf16x8 a;
      a[0] = (short)f2bf(u0.x); a[1] = (short)f2bf(u0.y);
      a[2] = (short)f2bf(u0.z); a[3] = (short)f2bf(u0.w);
      a[4] = (short)f2bf(u1.x); a[5] = (short)f2bf(u1.y);
      a[6] = (short)f2bf(u1.z); a[7] = (short)f2bf(u1.w);
      #pragma unroll
      for (int nt = 0; nt < 4; nt++) {
        bf16x8 b = *(const bf16x8*)(sW1 + (ks * 4 + nt) * 512 + lane * 8);
        acc[nt] = MFMA(a, b, acc[nt]);
      }
    }

    // + b1, LayerNorm over 64 cols of each row (rows = quad*4+r, 16-lane groups)
    float v[4][4];
    #pragma unroll
    for (int nt = 0; nt < 4; nt++)
      #pragma unroll
      for (int r = 0; r < 4; r++) v[nt][r] = acc[nt][r] + b1v[nt];

    #pragma unroll
    for (int r = 0; r < 4; r++) {
      float s = v[0][r] + v[1][r] + v[2][r] + v[3][r];
      #pragma unroll
      for (int mk = 8; mk >= 1; mk >>= 1) s += __shfl_xor(s, mk, 64);
      float mu = s * (1.f / 64.f);
      float q = 0.f;
      #pragma unroll
      for (int nt = 0; nt < 4; nt++) { float d = v[nt][r] - mu; q += d * d; }
      #pragma unroll
      for (int mk = 8; mk >= 1; mk >>= 1) q += __shfl_xor(q, mk, 64);
      float rs = rsqrtf(q * (1.f / 64.f) + EPS);
      #pragma unroll
      for (int nt = 0; nt < 4; nt++) {
        float h1 = fmaxf(fmaf((v[nt][r] - mu) * rs, g1v[nt], be1v[nt]), 0.f);
        st[wave][(quad * 4 + r) * 72 + nt * 16 + col0] = f2bf(h1);
      }
    }
    __builtin_amdgcn_wave_barrier();

    f32x4 acc2[4] = {};
    #pragma unroll
    for (int ks = 0; ks < 2; ks++) {
      bf16x8 a2 = *(const bf16x8*)(st[wave] + m * 72 + ks * 32 + koff);
      #pragma unroll
      for (int nt = 0; nt < 4; nt++) {
        bf16x8 b = *(const bf16x8*)(sW2 + (ks * 4 + nt) * 512 + lane * 8);
        acc2[nt] = MFMA(a2, b, acc2[nt]);
      }
    }
    __builtin_amdgcn_wave_barrier();

    #pragma unroll
    for (int nt = 0; nt < 4; nt++)
      #pragma unroll
      for (int r = 0; r < 4; r++) {
        int row = n0 + quad * 4 + r;
        if (row < N)
          hb[(size_t)row * 64 + nt * 16 + col0] = f2bf(fmaxf(acc2[nt][r] + b2v[nt], 0.f));
      }
  }
}

// ---- stage B+C (MFMA): edge MLP + coalesced atomic segment-sum ----
__launch_bounds__(256, 3)
__global__ void k_edge(const float* __restrict__ te, const u16* __restrict__ hb,
                       const float* __restrict__ wbuf, const u16* __restrict__ frags,
                       float* __restrict__ agg, int E, int N) {
  __shared__ __align__(16) u16 sWm1[24 * 512];
  __shared__ __align__(16) u16 sWm2[8 * 512];
  __shared__ __align__(16) u16 srel[576];
  __shared__ __align__(16) u16 st[4][16 * 72];

  {
    const uint4* s1 = (const uint4*)(frags + FR_Wm1);
    uint4* d1 = (uint4*)sWm1;
    for (int i = threadIdx.x; i < 1536; i += 256) d1[i] = s1[i];
    const uint4* s2 = (const uint4*)(frags + FR_Wm2);
    uint4* d2 = (uint4*)sWm2;
    for (int i = threadIdx.x; i < 512; i += 256) d2[i] = s2[i];
    const uint4* s3 = (const uint4*)(frags + FR_rel);
    uint4* d3 = (uint4*)srel;
    for (int i = threadIdx.x; i < 72; i += 256) d3[i] = s3[i];
  }
  __syncthreads();

  int lane = threadIdx.x & 63, wave = threadIdx.x >> 6;
  int m = lane & 15, quad = lane >> 4, koff = quad * 8, col0 = m;

  float bm1v[4], w192v[4], bm2v[4];
  #pragma unroll
  for (int nt = 0; nt < 4; nt++) {
    int c = nt * 16 + col0;
    bm1v[nt] = wbuf[OB_bm1 + c];
    w192v[nt] = wbuf[OB_w192 + c];
    bm2v[nt] = wbuf[OB_bm2 + c];
  }

  int ntiles = (E + 15) / 16;
  int wid = blockIdx.x * 4 + wave, nw = gridDim.x * 4;
  for (int tile = wid; tile < ntiles; tile += nw) {
    int e0 = tile * 16;
    int src = 0, dst = 0, rel = 0; float w = 0.f;
    if (lane < 16) {
      int e = min(e0 + lane, E - 1);
      float4 v = *(const float4*)(te + (size_t)e * 4);
      src = min(max((int)v.x, 0), N - 1);
      dst = min(max((int)v.y, 0), N - 1);
      rel = min(max((int)v.z, 0), 6);
      w = v.w;
    }
    int src_m = __shfl(src, m, 64);
    int dst_m = __shfl(dst, m, 64);
    int rel_m = __shfl(rel, m, 64);

    const u16* hs = hb + (size_t)src_m * 64;
    const u16* hd = hb + (size_t)dst_m * 64;
    bf16x8 af[6];
    af[0] = *(const bf16x8*)(hs + koff);
    af[1] = *(const bf16x8*)(hs + 32 + koff);
    af[2] = *(const bf16x8*)(hd + koff);
    af[3] = *(const bf16x8*)(hd + 32 + koff);
    af[4] = *(const bf16x8*)(srel + rel_m * 80 + koff);
    af[5] = *(const bf16x8*)(srel + rel_m * 80 + 32 + koff);

    f32x4 acc[4] = {};
    #pragma unroll
    for (int ks = 0; ks < 6; ks++) {
      #pragma unroll
      for (int nt = 0; nt < 4; nt++) {
        bf16x8 b = *(const bf16x8*)(sWm1 + (ks * 4 + nt) * 512 + lane * 8);
        acc[nt] = MFMA(af[ks], b, acc[nt]);
      }
    }

    // epilogue 1: + bm1 + w*Wm1[192], relu, write t to LDS (bf16)
    float wrow[4];
    #pragma unroll
    for (int r = 0; r < 4; r++) wrow[r] = __shfl(w, quad * 4 + r, 64);
    #pragma unroll
    for (int nt = 0; nt < 4; nt++)
      #pragma unroll
      for (int r = 0; r < 4; r++) {
        float v = fmaf(wrow[r], w192v[nt], acc[nt][r] + bm1v[nt]);
        st[wave][(quad * 4 + r) * 72 + nt * 16 + col0] = f2bf(fmaxf(v, 0.f));
      }
    __builtin_amdgcn_wave_barrier();

    f32x4 acc2[4] = {};
    #pragma unroll
    for (int ks = 0; ks < 2; ks++) {
      bf16x8 a2 = *(const bf16x8*)(st[wave] + m * 72 + ks * 32 + koff);
      #pragma unroll
      for (int nt = 0; nt < 4; nt++) {
        bf16x8 b = *(const bf16x8*)(sWm2 + (ks * 4 + nt) * 512 + lane * 8);
        acc2[nt] = MFMA(a2, b, acc2[nt]);
      }
    }
    __builtin_amdgcn_wave_barrier();

    // scatter: + bm2, coalesced atomics (16 consecutive floats per edge-row)
    int dstr[4]; bool valr[4];
    #pragma unroll
    for (int r = 0; r < 4; r++) {
      int row = quad * 4 + r;
      dstr[r] = __shfl(dst, row, 64);
      valr[r] = (e0 + row) < E;
    }
    #pragma unroll
    for (int nt = 0; nt < 4; nt++)
      #pragma unroll
      for (int r = 0; r < 4; r++)
        if (valr[r])
          atomicAdd(agg + (size_t)dstr[r] * 64 + nt * 16 + col0, acc2[nt][r] + bm2v[nt]);
  }
}

// ---- stage D1: nodes = LN(h+agg); global column sum + max ----
__launch_bounds__(256)
__global__ void k_nodes(const u16* __restrict__ hb, const float* __restrict__ agg,
                        const float* __restrict__ wbuf, float* __restrict__ gsum,
                        u32* __restrict__ gmax, int N) {
  int lane = threadIdx.x & 63, wave = threadIdx.x >> 6;
  int wid = blockIdx.x * 4 + wave;
  int nw = gridDim.x * 4;
  float gn = wbuf[OB_gn + lane], bn = wbuf[OB_bn + lane];
  float sj = 0.f, mj = -3.0e38f;
  for (int n = wid; n < N; n += nw) {
    float v = bf2f(hb[(size_t)n * 64 + lane]) + agg[(size_t)n * 64 + lane];
    float s = v;
    #pragma unroll
    for (int m = 32; m >= 1; m >>= 1) s += __shfl_xor(s, m, 64);
    float mu = s * (1.f / 64.f);
    float d = v - mu;
    float q = d * d;
    #pragma unroll
    for (int m = 32; m >= 1; m >>= 1) q += __shfl_xor(q, m, 64);
    float rs = rsqrtf(q * (1.f / 64.f) + EPS);
    float val = fmaf(d * rs, gn, bn);
    sj += val;
    mj = fmaxf(mj, val);
  }
  __shared__ float bs[256], bm[256];
  bs[threadIdx.x] = sj;
  bm[threadIdx.x] = mj;
  __syncthreads();
  if (threadIdx.x < 64) {
    int t = threadIdx.x;
    float ts = bs[t] + bs[64 + t] + bs[128 + t] + bs[192 + t];
    float tm = fmaxf(fmaxf(bm[t], bm[64 + t]), fmaxf(bm[128 + t], bm[192 + t]));
    atomicAdd(gsum + t, ts);
    atomicMax(gmax + t, fkey(tm));
  }
}

// ---- stage D2: g=[mean,max]; out = relu(g@Wg1+bg1)@Wg2+bg2 (fp32 out) ----
__launch_bounds__(128)
__global__ void k_final(const float* __restrict__ wbuf, const float* __restrict__ gsum,
                        const u32* __restrict__ gmax, float* __restrict__ out, int N) {
  __shared__ float g[128];
  __shared__ float y1[64];
  int t = threadIdx.x;
  if (t < 64) {
    g[t] = gsum[t] / (float)N;
  } else {
    u32 k = gmax[t - 64];
    u32 b = (k & 0x80000000u) ? (k & 0x7fffffffu) : ~k;
    g[t] = __uint_as_float(b);
  }
  __syncthreads();
  if (t < 64) {
    float a = wbuf[OB_bg1 + t];
    for (int i = 0; i < 128; i++) a = fmaf(g[i], wbuf[OB_Wg1 + i * 64 + t], a);
    y1[t] = fmaxf(a, 0.f);
  }
  __syncthreads();
  if (t < 64) {
    float a = wbuf[OB_bg2 + t];
    for (int k = 0; k < 64; k++) a = fmaf(y1[k], wbuf[OB_Wg2 + k * 64 + t], a);
    out[t] = a;
  }
}

extern "C" void kernel_launch(void* const* d_in, const int* in_sizes, int n_in,
                              void* d_out, int out_size, void* d_ws, size_t ws_size,
                              hipStream_t stream) {
  const int N = in_sizes[0] / 256;
  const int E = in_sizes[1] / 4;

  char* ws = (char*)d_ws;
  size_t aggB = (size_t)N * 64 * 4;
  size_t hbB  = (size_t)N * 64 * 2;
  float* agg   = (float*)ws;
  u16*   hb    = (u16*)(ws + aggB);
  float* gsum  = (float*)(ws + aggB + hbB);        // 64 f32
  u32*   gmax  = (u32*)(ws + aggB + hbB + 256);    // 64 u32
  float* wbuf  = (float*)(ws + aggB + hbB + 512);
  u16*   frags = (u16*)(ws + aggB + hbB + 512 + (size_t)WB_TOT * 4);

  const float* X  = (const float*)d_in[0];
  const float* te = (const float*)d_in[1];

  hipLaunchKernelGGL(k_prep, dim3(64), dim3(256), 0, stream,
                     (const float*)d_in[2], (const float*)d_in[3], (const float*)d_in[4],
                     (const float*)d_in[5], (const float*)d_in[6], (const float*)d_in[7],
                     (const float*)d_in[8], (const float*)d_in[9], (const float*)d_in[10],
                     (const float*)d_in[11], (const float*)d_in[12], (const float*)d_in[13],
                     (const float*)d_in[14], (const float*)d_in[15], (const float*)d_in[16],
                     (const float*)d_in[17], (const float*)d_in[18], wbuf, frags);
  hipMemsetAsync(agg, 0, aggB, stream);
  hipMemsetAsync(gsum, 0, 512, stream);
  hipLaunchKernelGGL(k_h, dim3(640), dim3(256), 0, stream, X, wbuf, frags, hb, N);
  hipLaunchKernelGGL(k_edge, dim3(768), dim3(256), 0, stream, te, hb, wbuf, frags, agg, E, N);
  hipLaunchKernelGGL(k_nodes, dim3(2048), dim3(256), 0, stream, hb, agg, wbuf, gsum, gmax, N);
  hipLaunchKernelGGL(k_final, dim3(1), dim3(128), 0, stream, wbuf, gsum, gmax, (float*)d_out, N);
}